// Round 2
// baseline (1080.018 us; speedup 1.0000x reference)
//
#include <hip/hip_runtime.h>
#include <hip/hip_cooperative_groups.h>
#include <math.h>

namespace cg = cooperative_groups;

#define H 1024
#define V 50257
#define L 4096
#define NB 1024          // grid blocks
#define RPB 50           // vocab rows per block: ceil(V/NB)=50, 50*1024=51200>=50257

__device__ __forceinline__ float wave_sum(float v) {
    #pragma unroll
    for (int o = 32; o; o >>= 1) v += __shfl_down(v, o);
    return v;
}
__device__ __forceinline__ float wave_max(float v) {
    #pragma unroll
    for (int o = 32; o; o >>= 1) v = fmaxf(v, __shfl_down(v, o));
    return v;
}
__device__ __forceinline__ void lse_merge(float& m, float& s, float m2, float s2) {
    if (m2 == -INFINITY) return;
    if (m == -INFINITY) { m = m2; s = s2; return; }
    float nm = fmaxf(m, m2);
    s = s * expf(m - nm) + s2 * expf(m2 - nm);
    m = nm;
}
__device__ __forceinline__ float dot4(float4 a, float4 b) {
    return a.x * b.x + a.y * b.y + a.z * b.z + a.w * b.w;
}

__global__ void __launch_bounds__(256, 4)
fused_decoder(const int* __restrict__ y, const float* __restrict__ s_prev,
              const float* __restrict__ h_all, const float* __restrict__ emb_W,
              const float* __restrict__ align_W, const float* __restrict__ align_b,
              const float* __restrict__ new_W, const float* __restrict__ new_b,
              const float* __restrict__ W_ih, const float* __restrict__ b_ih,
              const float* __restrict__ W_hh, const float* __restrict__ b_hh,
              const float* __restrict__ out_W, const float* __restrict__ out_b,
              float* __restrict__ logp, float* __restrict__ h_out, float* __restrict__ a_out,
              float* __restrict__ ws_e, float* __restrict__ ws_cpart, float* __restrict__ ws_c,
              float* __restrict__ ws_x, float* __restrict__ ws_h, float2* __restrict__ ws_pairs)
{
    cg::grid_group grid = cg::this_grid();
    const int b = blockIdx.x, tid = threadIdx.x, lane = tid & 63, wave = tid >> 6;
    __shared__ float s_red[32];
    __shared__ float s_bc[2];
    __shared__ float s_h[H];

    // ---- S1: attention scores. wave per row l = 4b+wave ----
    {
        int l = 4 * b + wave;
        const float* hrow = h_all + (size_t)l * H;
        const float* Wh = align_W;
        const float* Ws = align_W + H;
        float acc = 0.f;
        #pragma unroll
        for (int it = 0; it < 4; ++it) {
            int k = it * 256 + lane * 4;
            float4 h4 = *(const float4*)(hrow + k);
            float4 w4 = *(const float4*)(Wh + k);
            float4 s4 = *(const float4*)(s_prev + k);
            float4 v4 = *(const float4*)(Ws + k);
            acc += dot4(h4, w4) + dot4(s4, v4);
        }
        acc = wave_sum(acc);
        if (lane == 0) ws_e[l] = acc + align_b[0];
    }
    grid.sync();   // 1

    // ---- S2: softmax stats (redundant per block) + a-out + context partial ----
    {
        float4 ev[4];
        float m = -INFINITY;
        #pragma unroll
        for (int i = 0; i < 4; ++i) {
            ev[i] = *(const float4*)(ws_e + 4 * tid + 1024 * i);
            m = fmaxf(m, fmaxf(fmaxf(ev[i].x, ev[i].y), fmaxf(ev[i].z, ev[i].w)));
        }
        m = wave_max(m);
        if (lane == 0) s_red[wave] = m;
        __syncthreads();
        if (tid == 0) {
            float mm = s_red[0];
            for (int w = 1; w < 4; ++w) mm = fmaxf(mm, s_red[w]);
            s_bc[0] = mm;
        }
        __syncthreads();
        float M = s_bc[0];
        float s = 0.f;
        #pragma unroll
        for (int i = 0; i < 4; ++i)
            s += expf(ev[i].x - M) + expf(ev[i].y - M) + expf(ev[i].z - M) + expf(ev[i].w - M);
        s = wave_sum(s);
        if (lane == 0) s_red[4 + wave] = s;
        __syncthreads();
        if (tid == 0) {
            float ss = 0.f;
            for (int w = 0; w < 4; ++w) ss += s_red[4 + w];
            s_bc[1] = ss;
        }
        __syncthreads();
        float invS = 1.0f / s_bc[1];

        // a for this block's 4 rows (recompute from e, tiny L2 reads)
        float a0 = expf(ws_e[4 * b + 0] - M) * invS;
        float a1 = expf(ws_e[4 * b + 1] - M) * invS;
        float a2 = expf(ws_e[4 * b + 2] - M) * invS;
        float a3 = expf(ws_e[4 * b + 3] - M) * invS;
        if (tid < 4) a_out[4 * b + tid] = (tid == 0) ? a0 : (tid == 1) ? a1 : (tid == 2) ? a2 : a3;

        // context partial: cols 4t..4t+3 over rows 4b..4b+3, coalesced write
        int c0 = 4 * tid;
        float4 r0 = *(const float4*)(h_all + (size_t)(4 * b + 0) * H + c0);
        float4 r1 = *(const float4*)(h_all + (size_t)(4 * b + 1) * H + c0);
        float4 r2 = *(const float4*)(h_all + (size_t)(4 * b + 2) * H + c0);
        float4 r3 = *(const float4*)(h_all + (size_t)(4 * b + 3) * H + c0);
        float4 acc4;
        acc4.x = a0 * r0.x + a1 * r1.x + a2 * r2.x + a3 * r3.x;
        acc4.y = a0 * r0.y + a1 * r1.y + a2 * r2.y + a3 * r3.y;
        acc4.z = a0 * r0.z + a1 * r1.z + a2 * r2.z + a3 * r3.z;
        acc4.w = a0 * r0.w + a1 * r1.w + a2 * r2.w + a3 * r3.w;
        *(float4*)(ws_cpart + (size_t)b * H + c0) = acc4;
    }
    grid.sync();   // 2

    // ---- S3: context reduce: block b -> column b (scattered L2 reads, 4MB resident) ----
    {
        float acc = 0.f;
        for (int g = tid; g < NB; g += 256) acc += ws_cpart[(size_t)g * H + b];
        acc = wave_sum(acc);
        if (lane == 0) s_red[wave] = acc;
        __syncthreads();
        if (tid == 0) ws_c[b] = s_red[0] + s_red[1] + s_red[2] + s_red[3];
    }
    grid.sync();   // 3

    // ---- S4: x[b] = new_W[b,:] . [emb || c] + new_b[b] ----
    {
        const float* row = new_W + (size_t)b * (2 * H);
        const float* emb = emb_W + (size_t)y[0] * H;
        int k = 4 * tid;
        float4 w0 = *(const float4*)(row + k);
        float4 e0 = *(const float4*)(emb + k);
        float4 w1 = *(const float4*)(row + H + k);
        float4 c1 = *(const float4*)(ws_c + k);
        float acc = dot4(w0, e0) + dot4(w1, c1);
        acc = wave_sum(acc);
        if (lane == 0) s_red[wave] = acc;
        __syncthreads();
        if (tid == 0) ws_x[b] = s_red[0] + s_red[1] + s_red[2] + s_red[3] + new_b[b];
    }
    grid.sync();   // 4

    // ---- S5: GRU cell: block b -> h[b] ----
    {
        int k = 4 * tid;
        float4 xv = *(const float4*)(ws_x + k);
        float4 sv = *(const float4*)(s_prev + k);
        float d[6];
        #pragma unroll
        for (int g = 0; g < 3; ++g) {
            float4 wi = *(const float4*)(W_ih + (size_t)(g * H + b) * H + k);
            float4 wh = *(const float4*)(W_hh + (size_t)(g * H + b) * H + k);
            d[g]     = dot4(wi, xv);
            d[3 + g] = dot4(wh, sv);
        }
        #pragma unroll
        for (int g = 0; g < 6; ++g) {
            float v = wave_sum(d[g]);
            if (lane == 0) s_red[wave * 6 + g] = v;
        }
        __syncthreads();
        if (tid == 0) {
            float D[6];
            #pragma unroll
            for (int g = 0; g < 6; ++g)
                D[g] = s_red[g] + s_red[6 + g] + s_red[12 + g] + s_red[18 + g];
            float ir = D[0] + b_ih[b],     hr = D[3] + b_hh[b];
            float iz = D[1] + b_ih[H + b], hz = D[4] + b_hh[H + b];
            float in_ = D[2] + b_ih[2 * H + b], hn = D[5] + b_hh[2 * H + b];
            float r = 1.f / (1.f + expf(-(ir + hr)));
            float z = 1.f / (1.f + expf(-(iz + hz)));
            float n = tanhf(in_ + r * hn);
            float h = (1.f - z) * n + z * s_prev[b];
            ws_h[b] = h;
            h_out[b] = h;
        }
    }
    grid.sync();   // 5

    // ---- S6: vocab logits: block b -> rows [50b, 50b+50), per-block LSE pair ----
    {
        for (int k = tid; k < H; k += 256) s_h[k] = ws_h[k];
        __syncthreads();
        float m = -INFINITY, s = 0.f;
        int v0 = b * RPB;
        #pragma unroll 1
        for (int r = 0; r < 13; ++r) {
            int off = wave + 4 * r;
            int v = v0 + off;
            if (off < RPB && v < V) {
                const float* row = out_W + (size_t)v * H;
                float acc = 0.f;
                #pragma unroll
                for (int it = 0; it < 4; ++it) {
                    int k = it * 256 + lane * 4;
                    float4 w4 = *(const float4*)(row + k);
                    float4 h4 = *(const float4*)(s_h + k);
                    acc += dot4(w4, h4);
                }
                acc = wave_sum(acc);
                if (lane == 0) {
                    float lg = acc + out_b[v];
                    logp[v] = lg;
                    lse_merge(m, s, lg, 1.0f);
                }
            }
        }
        if (lane == 0) { s_red[2 * wave] = m; s_red[2 * wave + 1] = s; }
        __syncthreads();
        if (tid == 0) {
            float M2 = s_red[0], S2 = s_red[1];
            for (int w = 1; w < 4; ++w) lse_merge(M2, S2, s_red[2 * w], s_red[2 * w + 1]);
            ws_pairs[b] = make_float2(M2, S2);
        }
    }
    grid.sync();   // 6

    // ---- S7: redundant LSE combine (8KB L2 per block) + normalize own rows ----
    {
        float m = -INFINITY, s = 0.f;
        for (int i = tid; i < NB; i += 256) {
            float2 p = ws_pairs[i];
            lse_merge(m, s, p.x, p.y);
        }
        #pragma unroll
        for (int o = 32; o; o >>= 1) {
            float m2 = __shfl_down(m, o);
            float s2 = __shfl_down(s, o);
            lse_merge(m, s, m2, s2);
        }
        if (lane == 0) { s_red[2 * wave] = m; s_red[2 * wave + 1] = s; }
        __syncthreads();
        if (tid == 0) {
            float M2 = s_red[0], S2 = s_red[1];
            for (int w = 1; w < 4; ++w) lse_merge(M2, S2, s_red[2 * w], s_red[2 * w + 1]);
            s_bc[0] = M2 + logf(S2);
        }
        __syncthreads();
        float sub = s_bc[0];
        int v0 = b * RPB;
        for (int v = v0 + tid; v < v0 + RPB && v < V; v += 256)
            logp[v] -= sub;
    }
}

extern "C" void kernel_launch(void* const* d_in, const int* in_sizes, int n_in,
                              void* d_out, int out_size, void* d_ws, size_t ws_size,
                              hipStream_t stream) {
    const int*   y       = (const int*)d_in[0];
    const float* s_prev  = (const float*)d_in[1];
    const float* h_all   = (const float*)d_in[2];
    const float* emb_W   = (const float*)d_in[3];
    const float* align_W = (const float*)d_in[4];
    const float* align_b = (const float*)d_in[5];
    const float* new_W   = (const float*)d_in[6];
    const float* new_b   = (const float*)d_in[7];
    const float* W_ih    = (const float*)d_in[8];
    const float* b_ih    = (const float*)d_in[9];
    const float* W_hh    = (const float*)d_in[10];
    const float* b_hh    = (const float*)d_in[11];
    const float* out_W   = (const float*)d_in[12];
    const float* out_b   = (const float*)d_in[13];

    float* out      = (float*)d_out;
    float* logp_out = out;            // V
    float* h_out    = out + V;        // H
    float* a_out    = out + V + H;    // L

    // ws floats: e[4096] | cpart[1024*1024] | c[1024] | x[1024] | h[1024] | pairs[1024 float2]
    float*  ws        = (float*)d_ws;
    float*  ws_e      = ws;
    float*  ws_cpart  = ws + 4096;
    float*  ws_c      = ws_cpart + NB * H;
    float*  ws_x      = ws_c + H;
    float*  ws_h      = ws_x + H;
    float2* ws_pairs  = (float2*)(ws_h + H);

    void* args[] = {
        (void*)&y, (void*)&s_prev, (void*)&h_all, (void*)&emb_W,
        (void*)&align_W, (void*)&align_b, (void*)&new_W, (void*)&new_b,
        (void*)&W_ih, (void*)&b_ih, (void*)&W_hh, (void*)&b_hh,
        (void*)&out_W, (void*)&out_b,
        (void*)&logp_out, (void*)&h_out, (void*)&a_out,
        (void*)&ws_e, (void*)&ws_cpart, (void*)&ws_c,
        (void*)&ws_x, (void*)&ws_h, (void*)&ws_pairs
    };
    hipLaunchCooperativeKernel((const void*)fused_decoder, dim3(NB), dim3(256),
                               args, 0, stream);
}

// Round 3
// 441.369 us; speedup vs baseline: 2.4470x; 2.4470x over previous
//
#include <hip/hip_runtime.h>
#include <math.h>

#define H 1024
#define V 50257
#define L 4096
#define LOGITS_BLOCKS ((V + 15) / 16)   // 3142
#define FINAL_BLOCKS  ((V + 255) / 256) // 197

__device__ __forceinline__ float wave_sum(float v) {
    #pragma unroll
    for (int o = 32; o; o >>= 1) v += __shfl_down(v, o);
    return v;
}
__device__ __forceinline__ float wave_max(float v) {
    #pragma unroll
    for (int o = 32; o; o >>= 1) v = fmaxf(v, __shfl_down(v, o));
    return v;
}
__device__ __forceinline__ void lse_merge(float& m, float& s, float m2, float s2) {
    if (m2 == -INFINITY) return;
    if (m == -INFINITY) { m = m2; s = s2; return; }
    float nm = fmaxf(m, m2);
    s = s * expf(m - nm) + s2 * expf(m2 - nm);
    m = nm;
}
__device__ __forceinline__ float dot4(float4 a, float4 b) {
    return a.x * b.x + a.y * b.y + a.z * b.z + a.w * b.w;
}

// 1) e[l] = h_all[l]·Wh + s_prev·Ws + b  (wave per row); block 0 also zeros c
__global__ void k_scores(const float* __restrict__ h_all, const float* __restrict__ s_prev,
                         const float* __restrict__ align_W, const float* __restrict__ align_b,
                         float* __restrict__ e, float* __restrict__ c_ws) {
    int wave = threadIdx.x >> 6, lane = threadIdx.x & 63;
    if (blockIdx.x == 0) *(float4*)(c_ws + 4 * threadIdx.x) = make_float4(0.f, 0.f, 0.f, 0.f);
    int l = blockIdx.x * 4 + wave;
    const float* hrow = h_all + (size_t)l * H;
    const float* Wh = align_W;
    const float* Ws = align_W + H;
    float acc = 0.f;
    #pragma unroll
    for (int it = 0; it < 4; ++it) {
        int k = it * 256 + lane * 4;
        float4 h4 = *(const float4*)(hrow + k);
        float4 w4 = *(const float4*)(Wh + k);
        float4 s4 = *(const float4*)(s_prev + k);
        float4 v4 = *(const float4*)(Ws + k);
        acc += dot4(h4, w4) + dot4(s4, v4);
    }
    acc = wave_sum(acc);
    if (lane == 0) e[l] = acc + align_b[0];
}

// 2) fused softmax + context partial: 256 blocks x 1024 threads.
//    Each block redundantly computes softmax stats over e (16 KB from L2),
//    writes a for its 16 rows, and atomically accumulates its context partial.
__global__ void k_ctx(const float* __restrict__ e, const float* __restrict__ h_all,
                      float* __restrict__ a_out, float* __restrict__ c_ws) {
    __shared__ float red[16];
    __shared__ float s_bc[2];
    __shared__ float s_a[16];
    int tid = threadIdx.x, lane = tid & 63, wave = tid >> 6;
    float4 ev = *(const float4*)(e + 4 * tid);
    float m = fmaxf(fmaxf(ev.x, ev.y), fmaxf(ev.z, ev.w));
    m = wave_max(m);
    if (lane == 0) red[wave] = m;
    __syncthreads();
    if (tid == 0) {
        float mm = red[0];
        for (int w = 1; w < 16; ++w) mm = fmaxf(mm, red[w]);
        s_bc[0] = mm;
    }
    __syncthreads();
    float M = s_bc[0];
    float s = expf(ev.x - M) + expf(ev.y - M) + expf(ev.z - M) + expf(ev.w - M);
    s = wave_sum(s);
    __syncthreads();
    if (lane == 0) red[wave] = s;
    __syncthreads();
    if (tid == 0) {
        float ss = 0.f;
        for (int w = 0; w < 16; ++w) ss += red[w];
        s_bc[1] = ss;
    }
    __syncthreads();
    float invS = 1.0f / s_bc[1];
    int l0 = blockIdx.x * 16;
    if (tid < 16) {
        float av = expf(e[l0 + tid] - M) * invS;
        s_a[tid] = av;
        a_out[l0 + tid] = av;
    }
    __syncthreads();
    float acc = 0.f;
    #pragma unroll
    for (int r = 0; r < 16; ++r)
        acc += s_a[r] * h_all[(size_t)(l0 + r) * H + tid];
    atomicAdd(c_ws + tid, acc);
}

// 3) x[i] = new_W[i,:] · [emb ‖ c] + new_b[i]   (wave per row, dot over 2048)
__global__ void k_xvec(const float* __restrict__ new_W, const float* __restrict__ new_b,
                       const float* __restrict__ emb_W, const int* __restrict__ y,
                       const float* __restrict__ c, float* __restrict__ x) {
    int wave = threadIdx.x >> 6, lane = threadIdx.x & 63;
    int i = blockIdx.x * 4 + wave;
    const float* row = new_W + (size_t)i * (2 * H);
    const float* emb = emb_W + (size_t)y[0] * H;
    float acc = 0.f;
    #pragma unroll
    for (int it = 0; it < 8; ++it) {
        int k = it * 256 + lane * 4;
        float4 w4 = *(const float4*)(row + k);
        float4 v4 = (k < H) ? *(const float4*)(emb + k) : *(const float4*)(c + (k - H));
        acc += dot4(w4, v4);
    }
    acc = wave_sum(acc);
    if (lane == 0) x[i] = acc + new_b[i];
}

// 4) fused GRU: block per output i, 6 waves = 6 row-dots; writes h to ws and out
__global__ void k_gru(const float* __restrict__ W_ih, const float* __restrict__ b_ih,
                      const float* __restrict__ W_hh, const float* __restrict__ b_hh,
                      const float* __restrict__ x, const float* __restrict__ s_prev,
                      float* __restrict__ h_ws, float* __restrict__ h_out) {
    __shared__ float dots[6];
    int wave = threadIdx.x >> 6, lane = threadIdx.x & 63;
    int i = blockIdx.x;
    int g = wave % 3;
    const float* row;
    const float* vec;
    if (wave < 3) { row = W_ih + (size_t)(g * H + i) * H; vec = x; }
    else          { row = W_hh + (size_t)(g * H + i) * H; vec = s_prev; }
    float acc = 0.f;
    #pragma unroll
    for (int it = 0; it < 4; ++it) {
        int k = it * 256 + lane * 4;
        float4 w4 = *(const float4*)(row + k);
        float4 v4 = *(const float4*)(vec + k);
        acc += dot4(w4, v4);
    }
    acc = wave_sum(acc);
    if (lane == 0) dots[wave] = acc;
    __syncthreads();
    if (threadIdx.x == 0) {
        float ir  = dots[0] + b_ih[i];
        float iz  = dots[1] + b_ih[H + i];
        float in_ = dots[2] + b_ih[2 * H + i];
        float hr  = dots[3] + b_hh[i];
        float hz  = dots[4] + b_hh[H + i];
        float hn  = dots[5] + b_hh[2 * H + i];
        float r = 1.f / (1.f + expf(-(ir + hr)));
        float z = 1.f / (1.f + expf(-(iz + hz)));
        float n = tanhf(in_ + r * hn);
        float h = (1.f - z) * n + z * s_prev[i];
        h_ws[i]  = h;
        h_out[i] = h;
    }
}

// 5) logits[v] = out_W[v,:]·h + out_b[v]; per-block online (m,s) pair
__global__ void k_logits(const float* __restrict__ out_W, const float* __restrict__ out_b,
                         const float* __restrict__ h, float* __restrict__ logits,
                         float2* __restrict__ pairs) {
    __shared__ float sh_h[H];
    __shared__ float2 wpair[4];
    for (int k = threadIdx.x; k < H; k += 256) sh_h[k] = h[k];
    __syncthreads();
    int wave = threadIdx.x >> 6, lane = threadIdx.x & 63;
    float m = -INFINITY, s = 0.f;
    #pragma unroll
    for (int rr = 0; rr < 4; ++rr) {
        int v = blockIdx.x * 16 + wave * 4 + rr;
        if (v >= V) continue;   // uniform within a wave
        const float* row = out_W + (size_t)v * H;
        float acc = 0.f;
        #pragma unroll
        for (int it = 0; it < 4; ++it) {
            int k = it * 256 + lane * 4;
            float4 w4 = *(const float4*)(row + k);
            float4 h4 = *(const float4*)(sh_h + k);
            acc += dot4(w4, h4);
        }
        acc = wave_sum(acc);
        if (lane == 0) {
            float lg = acc + out_b[v];
            logits[v] = lg;
            lse_merge(m, s, lg, 1.0f);
        }
    }
    if (lane == 0) wpair[wave] = make_float2(m, s);
    __syncthreads();
    if (threadIdx.x == 0) {
        float M = wpair[0].x, S = wpair[0].y;
        for (int w = 1; w < 4; ++w) lse_merge(M, S, wpair[w].x, wpair[w].y);
        pairs[blockIdx.x] = make_float2(M, S);
    }
}

// 6) fused combine+finalize: each of 197 blocks redundantly LSE-reduces the
//    3142 pairs (25 KB, L2-hit) then normalizes its own 256 logits.
__global__ void k_final(const float2* __restrict__ pairs, float* __restrict__ logits) {
    __shared__ float redm[4];
    __shared__ float reds[4];
    __shared__ float s_sub;
    int tid = threadIdx.x, lane = tid & 63, wave = tid >> 6;
    float m = -INFINITY, s = 0.f;
    for (int i = tid; i < LOGITS_BLOCKS; i += 256) {
        float2 p = pairs[i];
        lse_merge(m, s, p.x, p.y);
    }
    #pragma unroll
    for (int o = 32; o; o >>= 1) {
        float m2 = __shfl_down(m, o);
        float s2 = __shfl_down(s, o);
        lse_merge(m, s, m2, s2);
    }
    if (lane == 0) { redm[wave] = m; reds[wave] = s; }
    __syncthreads();
    if (tid == 0) {
        float M = redm[0], S = reds[0];
        for (int w = 1; w < 4; ++w) lse_merge(M, S, redm[w], reds[w]);
        s_sub = M + logf(S);
    }
    __syncthreads();
    int v = blockIdx.x * 256 + tid;
    if (v < V) logits[v] -= s_sub;
}

extern "C" void kernel_launch(void* const* d_in, const int* in_sizes, int n_in,
                              void* d_out, int out_size, void* d_ws, size_t ws_size,
                              hipStream_t stream) {
    const int*   y       = (const int*)d_in[0];
    const float* s_prev  = (const float*)d_in[1];
    const float* h_all   = (const float*)d_in[2];
    const float* emb_W   = (const float*)d_in[3];
    const float* align_W = (const float*)d_in[4];
    const float* align_b = (const float*)d_in[5];
    const float* new_W   = (const float*)d_in[6];
    const float* new_b   = (const float*)d_in[7];
    const float* W_ih    = (const float*)d_in[8];
    const float* b_ih    = (const float*)d_in[9];
    const float* W_hh    = (const float*)d_in[10];
    const float* b_hh    = (const float*)d_in[11];
    const float* out_W   = (const float*)d_in[12];
    const float* out_b   = (const float*)d_in[13];

    float* out      = (float*)d_out;
    float* logp_out = out;            // V
    float* h_out    = out + V;        // H
    float* a_out    = out + V + H;    // L

    // ws floats: e[4096] c[1024] x[1024] h[1024] pairs[LOGITS_BLOCKS float2]
    float*  ws       = (float*)d_ws;
    float*  ws_e     = ws;
    float*  ws_c     = ws + 4096;
    float*  ws_x     = ws + 5120;
    float*  ws_h     = ws + 6144;
    float2* ws_pairs = (float2*)(ws + 7168);

    k_scores<<<L / 4, 256, 0, stream>>>(h_all, s_prev, align_W, align_b, ws_e, ws_c);
    k_ctx   <<<L / 16, 1024, 0, stream>>>(ws_e, h_all, a_out, ws_c);
    k_xvec  <<<H / 4, 256, 0, stream>>>(new_W, new_b, emb_W, y, ws_c, ws_x);
    k_gru   <<<H, 384, 0, stream>>>(W_ih, b_ih, W_hh, b_hh, ws_x, s_prev, ws_h, h_out);
    k_logits<<<LOGITS_BLOCKS, 256, 0, stream>>>(out_W, out_b, ws_h, logp_out, ws_pairs);
    k_final <<<FINAL_BLOCKS, 256, 0, stream>>>(ws_pairs, logp_out);
}